// Round 19
// baseline (188.402 us; speedup 1.0000x reference)
//
#include <hip/hip_runtime.h>

// SABlock: EGNN-style block. N=4, L=256, D=128, P=64, C=4.
//   k_prep      : norm_partial | pack coord/msg/edge/coordW2 frags | pre_hA | h->bf16
//                 (v15: z->bf16 prep REMOVED — 100MB of traffic whose only benefit was
//                 R9-era spill relief; consumers now cvt8 fp32 z directly, VGPR 52 has room)
//   k_norm_finish : rnorm[16]
//   k_msg_mfma  : GEMM1 -> silu -> GEMM2 (m in LDS only) -> agg partials -> coord MLPs on MFMA
//   k_node      : node MLP + LayerNorm + coord finalize + agg sum + fused eA/eB
//   k_edge_mfma : jh-split (2048 blocks)

#define DEV static __device__ __forceinline__

// Fast silu: x * rcp(1+exp(-x)); ~1ulp rcp error invisible after bf16 truncation.
DEV float silu(float x) {
    const float e = __expf(-x);
    return x * __builtin_amdgcn_rcpf(1.0f + e);
}

DEV float bf2f(unsigned short u) {
    unsigned int v = ((unsigned int)u) << 16;
    float f;
    __builtin_memcpy(&f, &v, 4);
    return f;
}
DEV unsigned short f2bf(float f) {
    unsigned int x;
    __builtin_memcpy(&x, &f, 4);
    x += 0x7fffu + ((x >> 16) & 1u);
    return (unsigned short)(x >> 16);
}

struct __align__(8) US4 { unsigned short x, y, z, w; };

typedef __bf16 bf16x8 __attribute__((ext_vector_type(8)));
typedef float  f32x4  __attribute__((ext_vector_type(4)));

DEV bf16x8 cvt8(const float* p) {
    const float4 a = *reinterpret_cast<const float4*>(p);
    const float4 c = *reinterpret_cast<const float4*>(p + 4);
    bf16x8 r;
    r[0] = (__bf16)a.x; r[1] = (__bf16)a.y; r[2] = (__bf16)a.z; r[3] = (__bf16)a.w;
    r[4] = (__bf16)c.x; r[5] = (__bf16)c.y; r[6] = (__bf16)c.z; r[7] = (__bf16)c.w;
    return r;
}

// ---------------- fat prep kernel ----------------
// blk ranges: [0,1024) norm_partial | [1024,1152) pack coord w1 | [1152,1328) pack msg
//             [1328,1392) pack edge | [1392,1904) pre_hA | [1904,1920) pack coord W2
//             [1920,1984) h->bf16
__global__ __launch_bounds__(256) void k_prep(
    const float* __restrict__ coord, const float* __restrict__ h,
    const float* __restrict__ msg_w1, const float* __restrict__ msg_b1,
    const float* __restrict__ msg_w2,
    const float* __restrict__ edge_w1, const float* __restrict__ edge_w2,
    const float* __restrict__ c0w1, const float* __restrict__ c1w1,
    const float* __restrict__ c0w2, const float* __restrict__ c1w2,
    float* __restrict__ partial, float* __restrict__ hA,
    unsigned short* __restrict__ wsA, unsigned short* __restrict__ wsMsgA,
    unsigned short* __restrict__ wsW2A,
    unsigned short* __restrict__ wE1A, unsigned short* __restrict__ wEW2A,
    unsigned short* __restrict__ wsCW2,
    unsigned short* __restrict__ h_bf)
{
    const int blk = blockIdx.x;
    const int t = threadIdx.x;
    __shared__ float red[4][16];
    __shared__ float hl2[2][128];

    if (blk < 1024) {
        const int r = blk * 256 + t;
        const int b = r >> 16, rem = r & 0xFFFF, i = rem >> 8, j = rem & 255;
        const float* ci = coord + (b * 256 + i) * 12;
        const float* cj = coord + (b * 256 + j) * 12;
        float cd[4][3];
        #pragma unroll
        for (int c = 0; c < 4; ++c)
            #pragma unroll
            for (int x = 0; x < 3; ++x)
                cd[c][x] = ci[c * 3 + x] - cj[c * 3 + x];
        float sq[16];
        #pragma unroll
        for (int m = 0; m < 4; ++m)
            #pragma unroll
            for (int p = 0; p < 4; ++p) {
                float v = cd[m][0] * cd[p][0] + cd[m][1] * cd[p][1] + cd[m][2] * cd[p][2];
                sq[m * 4 + p] = v * v;
            }
        #pragma unroll
        for (int s = 1; s < 64; s <<= 1)
            #pragma unroll
            for (int qq = 0; qq < 16; ++qq)
                sq[qq] += __shfl_xor(sq[qq], s, 64);
        const int wave = t >> 6, lane = t & 63;
        if (lane == 0)
            #pragma unroll
            for (int qq = 0; qq < 16; ++qq) red[wave][qq] = sq[qq];
        __syncthreads();
        if (t < 16)
            partial[blk * 16 + t] = red[0][t] + red[1][t] + red[2][t] + red[3][t];
    } else if (blk < 1152) {
        const int o = (blk - 1024) * 256 + t;         // < 32768
        const int p  = o >> 14;
        const int r  = o & 16383;
        const int jj = r & 7, l = (r >> 3) & 63, rf = (r >> 9) & 7, kk = r >> 12;
        const int k = kk * 32 + ((l >> 4) << 3) + jj;
        const int c = (rf << 4) + (l & 15);
        const float* W = p ? c1w1 : c0w1;
        wsA[o] = f2bf(W[k * 128 + c]);
    } else if (blk < 1328) {
        const int o = (blk - 1152) * 256 + t;         // < 45056
        if (o < 16384) {
            const int jj = o & 7, l = (o >> 3) & 63, rf = (o >> 9) & 7, kk = o >> 12;
            const int k = kk * 32 + ((l >> 4) << 3) + jj;
            const int c = (rf << 4) + (l & 15);
            wsMsgA[o] = f2bf(msg_w1[(128 + k) * 128 + c]);
        } else if (o < 20480) {
            const int o2 = o - 16384;
            const int jj = o2 & 7, l = (o2 >> 3) & 63, rf = (o2 >> 9) & 7;
            const int k = ((l >> 4) << 3) + jj;
            const int c = (rf << 4) + (l & 15);
            wsMsgA[o] = (k < 16) ? f2bf(msg_w1[(256 + k) * 128 + c]) : (unsigned short)0;
        } else if (o < 28672) {
            const int o3 = o - 20480;
            const int jj = o3 & 7, l = (o3 >> 3) & 63, rf = (o3 >> 9) & 7, kk = o3 >> 12;
            const int k = kk * 32 + ((l >> 4) << 3) + jj;
            const int c = (rf << 4) + (l & 15);
            wsMsgA[o] = f2bf(msg_w1[(272 + k) * 128 + c]);
        } else {
            const int o2 = o - 28672;                 // < 16384
            const int jj = o2 & 7, l = (o2 >> 3) & 63, rf = (o2 >> 9) & 7, kk2 = o2 >> 12;
            const int c  = kk2 * 32 + ((l >> 4) << 3) + jj;
            const int c2 = (rf << 4) + (l & 15);
            wsW2A[o2] = f2bf(msg_w2[c * 128 + c2]);
        }
    } else if (blk < 1392) {
        const int o = (blk - 1328) * 256 + t;         // < 16384
        if (o < 8192) {
            const int jj = o & 7, l = (o >> 3) & 63, rf = (o >> 9) & 7, kk = o >> 12;
            const int k = kk * 32 + ((l >> 4) << 3) + jj;
            const int c = (rf << 4) + (l & 15);
            wE1A[o] = f2bf(edge_w1[(256 + k) * 128 + c]);
        } else {
            const int o2 = o - 8192;
            const int jj = o2 & 7, l = (o2 >> 3) & 63, rf = (o2 >> 9) & 3, kk2 = o2 >> 11;
            const int k = kk2 * 32 + ((l >> 4) << 3) + jj;
            const int p = (rf << 4) + (l & 15);
            wEW2A[o2] = f2bf(edge_w2[k * 64 + p]);
        }
    } else if (blk < 1904) {
        const int rr = (blk - 1392) * 2 + (t >> 7);
        const int c = t & 127;
        hl2[t >> 7][c] = h[rr * 128 + c];
        __syncthreads();
        float acc = msg_b1[c];
        #pragma unroll 8
        for (int k = 0; k < 128; ++k) acc += hl2[t >> 7][k] * msg_w1[k * 128 + c];
        hA[rr * 128 + c] = acc;
    } else if (blk < 1920) {
        // coord W2 as zero-padded 16x128 A-frags: A[pr][k] = W2[k][pr] for pr<4 else 0
        const int o = (blk - 1904) * 256 + t;         // < 4096
        const int p = o >> 11;
        const int r = o & 2047;
        const int jj = r & 7, l = (r >> 3) & 63, kk = (r >> 9) & 3;
        const int k = kk * 32 + ((l >> 4) << 3) + jj;
        const int pr = l & 15;
        const float* W2 = p ? c1w2 : c0w2;
        wsCW2[o] = (pr < 4) ? f2bf(W2[k * 4 + pr]) : (unsigned short)0;
    } else {
        const int i0 = (blk - 1920) * 2048 + t * 8;   // < 131072
        const bf16x8 v = cvt8(h + i0);
        *reinterpret_cast<bf16x8*>(h_bf + i0) = v;
    }
}

__global__ __launch_bounds__(256) void k_norm_finish(const float* __restrict__ partial,
                                                     float* __restrict__ rnorm)
{
    const int t = threadIdx.x;
    const int cc = t & 15, g = t >> 4;
    float s = 0.f;
    for (int k = 0; k < 64; ++k) s += partial[(g * 64 + k) * 16 + cc];
    __shared__ float red[16][17];
    red[g][cc] = s;
    __syncthreads();
    if (t < 16) {
        float tot = 0.f;
        #pragma unroll
        for (int gg = 0; gg < 16; ++gg) tot += red[gg][t];
        rnorm[t] = 1.0f / fmaxf(sqrtf(tot), 1e-12f);
    }
}

// ---------------- message MLP + coord MLPs + aggregates, all fused (v15) ----------------
__global__ __launch_bounds__(512) void k_msg_mfma(
    const float* __restrict__ coord,
    const float* __restrict__ z,
    const unsigned short* __restrict__ h_bf,
    const float* __restrict__ hA,
    const unsigned short* __restrict__ wsMsgA,
    const unsigned short* __restrict__ wsW2A,
    const unsigned short* __restrict__ wsA,
    const unsigned short* __restrict__ wsCW2,
    const float* __restrict__ msg_b2, const float* __restrict__ rnorm,
    const float* __restrict__ intra, const float* __restrict__ inter,
    float* __restrict__ aggP, float* __restrict__ aggC)
{
    const int blk  = blockIdx.x;
    const int bi   = blk >> 1;
    const int jh   = blk & 1;            // which 128-row half of the (b,i) tile
    const int b    = bi >> 8;
    const int t    = threadIdx.x;
    const int w    = t >> 6, l = t & 63, g = l >> 4, l15 = l & 15;

    __shared__ __align__(16) unsigned short A1[20480];        // 40960 B: GEMM1 frags -> W2 frags -> coord frags
    __shared__ __align__(16) unsigned short hidm[128 * 136];  // 34816 B
    __shared__ float hAl[128], b2l[128];
    __shared__ float iml[128], eml[128];
    __shared__ float cil[12];
    __shared__ float rnl[16];
    __shared__ float redC[8][12];
    __shared__ float redD[8];

    {
        const float4* src = reinterpret_cast<const float4*>(wsMsgA);
        float4* dst = reinterpret_cast<float4*>(A1);
        #pragma unroll
        for (int it = 0; it < 5; ++it) dst[it * 512 + t] = src[it * 512 + t];  // 40 KB
    }
    if (t < 12) cil[t] = coord[bi * 12 + t];
    if (t < 16) rnl[t] = rnorm[t];
    if (t < 128)      hAl[t] = hA[bi * 128 + t];
    else if (t < 256) b2l[t - 128] = msg_b2[t - 128];
    else if (t < 384) iml[t - 256] = intra[(size_t)bi * 256 + jh * 128 + (t - 256)];
    else              eml[t - 384] = inter[(size_t)bi * 256 + jh * 128 + (t - 384)];
    __syncthreads();

    const int j   = jh * 128 + w * 16 + l15;   // j in [0,256)
    const int row = w * 16 + l15;
    const size_t rb = (size_t)row * 136;

    // rad B-frag inline (K=32 slot: k = g*8+e, real for k<16, zero-padded above)
    bf16x8 radB;
    {
        const float* cjp = coord + (size_t)(b * 256 + j) * 12;   // 48B rows, 16B-aligned
        const float4 cj0 = *reinterpret_cast<const float4*>(cjp);
        const float4 cj1 = *reinterpret_cast<const float4*>(cjp + 4);
        const float4 cj2 = *reinterpret_cast<const float4*>(cjp + 8);
        float cd[12];
        cd[0] = cil[0] - cj0.x; cd[1]  = cil[1]  - cj0.y; cd[2]  = cil[2]  - cj0.z;
        cd[3] = cil[3] - cj0.w; cd[4]  = cil[4]  - cj1.x; cd[5]  = cil[5]  - cj1.y;
        cd[6] = cil[6] - cj1.z; cd[7]  = cil[7]  - cj1.w; cd[8]  = cil[8]  - cj2.x;
        cd[9] = cil[9] - cj2.y; cd[10] = cil[10] - cj2.z; cd[11] = cil[11] - cj2.w;
        #pragma unroll
        for (int e = 0; e < 8; ++e) {
            const int k = g * 8 + e;
            float v = 0.f;
            if (k < 16) {
                const int mm = k >> 2, pp = k & 3;
                v = (cd[mm*3+0]*cd[pp*3+0] + cd[mm*3+1]*cd[pp*3+1] + cd[mm*3+2]*cd[pp*3+2]) * rnl[k];
            }
            radB[e] = (__bf16)v;
        }
    }

    // GEMM1: K=224, rf-halves (a1[4]); hj+rad frags from A1 LDS, z frags cvt8 from fp32
    #pragma unroll 1
    for (int rfh = 0; rfh < 2; ++rfh) {
        asm volatile("" ::: "memory");
        f32x4 a1[4];
        #pragma unroll
        for (int rf2 = 0; rf2 < 4; ++rf2) a1[rf2] = (f32x4){0.f, 0.f, 0.f, 0.f};

        #pragma unroll
        for (int kk = 0; kk < 4; ++kk) {
            const bf16x8 bf = *reinterpret_cast<const bf16x8*>(h_bf + (size_t)(b * 256 + j) * 128 + kk * 32 + g * 8);
            #pragma unroll
            for (int rf2 = 0; rf2 < 4; ++rf2)
                a1[rf2] = __builtin_amdgcn_mfma_f32_16x16x32_bf16(
                    *reinterpret_cast<const bf16x8*>(A1 + ((kk * 8 + rfh * 4 + rf2) * 64 + l) * 8), bf, a1[rf2], 0, 0, 0);
        }
        #pragma unroll
        for (int kk = 0; kk < 2; ++kk) {
            const bf16x8 bf = cvt8(z + (size_t)(bi * 256 + j) * 64 + kk * 32 + g * 8);
            #pragma unroll
            for (int rf2 = 0; rf2 < 4; ++rf2)
                a1[rf2] = __builtin_amdgcn_mfma_f32_16x16x32_bf16(
                    *reinterpret_cast<const bf16x8*>(wsMsgA + 20480 + ((kk * 8 + rfh * 4 + rf2) * 64 + l) * 8), bf, a1[rf2], 0, 0, 0);
        }
        #pragma unroll
        for (int rf2 = 0; rf2 < 4; ++rf2)
            a1[rf2] = __builtin_amdgcn_mfma_f32_16x16x32_bf16(
                *reinterpret_cast<const bf16x8*>(A1 + 16384 + ((rfh * 4 + rf2) * 64 + l) * 8), radB, a1[rf2], 0, 0, 0);

        // hidden = silu(acc + hA[c]) -> bf16 into this lane's hidm row (this half's columns)
        #pragma unroll
        for (int rf2 = 0; rf2 < 4; ++rf2) {
            const int cb = (rfh * 4 + rf2) * 16 + g * 4;
            union { __bf16 b4[4]; unsigned long long u; } pk;
            #pragma unroll
            for (int r = 0; r < 4; ++r) pk.b4[r] = (__bf16)silu(a1[rf2][r] + hAl[cb + r]);
            *reinterpret_cast<unsigned long long*>(hidm + rb + cb) = pk.u;
        }
    }

    // ---- stage GEMM2 W2 A-frags into A1's now-dead LDS ----
    __syncthreads();   // all waves' GEMM1 A1 reads complete
    {
        const float4* src = reinterpret_cast<const float4*>(wsW2A);
        float4* dst = reinterpret_cast<float4*>(A1);
        #pragma unroll
        for (int it = 0; it < 4; ++it) dst[it * 512 + t] = src[it * 512 + t];  // 32 KB
    }
    __syncthreads();

    // GEMM2: m^T = W2^T x hidden^T (W2 A-frags from LDS)
    {
        f32x4 a2[8];
        #pragma unroll
        for (int rf = 0; rf < 8; ++rf) a2[rf] = (f32x4){0.f, 0.f, 0.f, 0.f};
        #pragma unroll
        for (int kk2 = 0; kk2 < 4; ++kk2) {
            const bf16x8 bf2 = *reinterpret_cast<const bf16x8*>(hidm + rb + kk2 * 32 + g * 8);
            #pragma unroll
            for (int rf = 0; rf < 8; ++rf)
                a2[rf] = __builtin_amdgcn_mfma_f32_16x16x32_bf16(
                    *reinterpret_cast<const bf16x8*>(A1 + ((kk2 * 8 + rf) * 64 + l) * 8), bf2, a2[rf], 0, 0, 0);
        }
        __builtin_amdgcn_wave_barrier();

        // epilogue: +b2, pack m (bf16) over the hidm row. m stays in LDS only.
        #pragma unroll
        for (int rf = 0; rf < 8; ++rf) {
            const int cb = rf * 16 + g * 4;
            union { __bf16 b4[4]; unsigned long long u; } pk;
            #pragma unroll
            for (int r = 0; r < 4; ++r) pk.b4[r] = (__bf16)(a2[rf][r] + b2l[cb + r]);
            *reinterpret_cast<unsigned long long*>(hidm + rb + cb) = pk.u;
        }
    }

    __syncthreads();   // all hidm rows (m) visible; all A1 GEMM2 reads complete

    // ---- fused masked-aggregate partials: masks from LDS ----
    {
        const int c  = t & 127;
        const int jg = t >> 7;          // 0..3, rows jg*32 .. jg*32+31
        float aIp = 0.f, aEp = 0.f;
        #pragma unroll 8
        for (int r2 = 0; r2 < 32; ++r2) {
            const int row2 = jg * 32 + r2;
            const float mv = bf2f(hidm[(size_t)row2 * 136 + c]);
            aIp += mv * iml[row2];
            aEp += mv * eml[row2];
        }
        aggP[((size_t)blk * 4 + jg) * 256 + c]       = aIp;
        aggP[((size_t)blk * 4 + jg) * 256 + 128 + c] = aEp;
    }

    // ---- fused coord MLPs, fully on MFMA ----
    __syncthreads();   // agg done in all waves; A1 free for re-staging
    {
        const float4* src = reinterpret_cast<const float4*>(wsA);          // p0 w1 frags, 32 KB
        float4* dst = reinterpret_cast<float4*>(A1);
        #pragma unroll
        for (int it = 0; it < 4; ++it) dst[it * 512 + t] = src[it * 512 + t];
        const float4* srcW = reinterpret_cast<const float4*>(wsCW2);       // both W2 frag sets, 8 KB
        reinterpret_cast<float4*>(A1 + 16384)[t] = srcW[t];
    }
    __syncthreads();

    // m B-frags, read once, reused for both p (hidm rows are wave-local)
    bf16x8 bfm[4];
    #pragma unroll
    for (int kk2 = 0; kk2 < 4; ++kk2)
        bfm[kk2] = *reinterpret_cast<const bf16x8*>(hidm + rb + kk2 * 32 + g * 8);

    f32x4 aw0, aw1;
    {
        // p=0 GEMM1
        f32x4 ac[8];
        #pragma unroll
        for (int rf = 0; rf < 8; ++rf) ac[rf] = (f32x4){0.f, 0.f, 0.f, 0.f};
        #pragma unroll
        for (int kk2 = 0; kk2 < 4; ++kk2)
            #pragma unroll
            for (int rf = 0; rf < 8; ++rf)
                ac[rf] = __builtin_amdgcn_mfma_f32_16x16x32_bf16(
                    *reinterpret_cast<const bf16x8*>(A1 + ((kk2 * 8 + rf) * 64 + l) * 8), bfm[kk2], ac[rf], 0, 0, 0);
        #pragma unroll
        for (int rf = 0; rf < 8; ++rf) {
            const int cb = rf * 16 + g * 4;
            union { __bf16 b4[4]; unsigned long long u; } pk;
            #pragma unroll
            for (int r = 0; r < 4; ++r) pk.b4[r] = (__bf16)silu(ac[rf][r]);
            *reinterpret_cast<unsigned long long*>(hidm + rb + cb) = pk.u;
        }
        __builtin_amdgcn_wave_barrier();
        aw0 = (f32x4){0.f, 0.f, 0.f, 0.f};
        #pragma unroll
        for (int kk2 = 0; kk2 < 4; ++kk2) {
            const bf16x8 bh = *reinterpret_cast<const bf16x8*>(hidm + rb + kk2 * 32 + g * 8);
            aw0 = __builtin_amdgcn_mfma_f32_16x16x32_bf16(
                *reinterpret_cast<const bf16x8*>(A1 + 16384 + ((kk2 * 64) + l) * 8), bh, aw0, 0, 0, 0);
        }
    }
    __syncthreads();   // all A1 p0 reads done
    {
        const float4* src = reinterpret_cast<const float4*>(wsA + 16384);  // p1 w1 frags
        float4* dst = reinterpret_cast<float4*>(A1);
        #pragma unroll
        for (int it = 0; it < 4; ++it) dst[it * 512 + t] = src[it * 512 + t];
    }
    __syncthreads();
    {
        // p=1 GEMM1 (bfm still live)
        f32x4 ac[8];
        #pragma unroll
        for (int rf = 0; rf < 8; ++rf) ac[rf] = (f32x4){0.f, 0.f, 0.f, 0.f};
        #pragma unroll
        for (int kk2 = 0; kk2 < 4; ++kk2)
            #pragma unroll
            for (int rf = 0; rf < 8; ++rf)
                ac[rf] = __builtin_amdgcn_mfma_f32_16x16x32_bf16(
                    *reinterpret_cast<const bf16x8*>(A1 + ((kk2 * 8 + rf) * 64 + l) * 8), bfm[kk2], ac[rf], 0, 0, 0);
        #pragma unroll
        for (int rf = 0; rf < 8; ++rf) {
            const int cb = rf * 16 + g * 4;
            union { __bf16 b4[4]; unsigned long long u; } pk;
            #pragma unroll
            for (int r = 0; r < 4; ++r) pk.b4[r] = (__bf16)silu(ac[rf][r]);
            *reinterpret_cast<unsigned long long*>(hidm + rb + cb) = pk.u;
        }
        __builtin_amdgcn_wave_barrier();
        aw1 = (f32x4){0.f, 0.f, 0.f, 0.f};
        #pragma unroll
        for (int kk2 = 0; kk2 < 4; ++kk2) {
            const bf16x8 bh = *reinterpret_cast<const bf16x8*>(hidm + rb + kk2 * 32 + g * 8);
            aw1 = __builtin_amdgcn_mfma_f32_16x16x32_bf16(
                *reinterpret_cast<const bf16x8*>(A1 + 16384 + 2048 + ((kk2 * 64) + l) * 8), bh, aw1, 0, 0, 0);
        }
    }

    // epilogue: g==0 lanes hold wt rows 0..3 (channels) for col l15 = their j
    if (g == 0) {
        const float im = iml[row];
        const float em = eml[row];
        float wt[4];
        #pragma unroll
        for (int pc = 0; pc < 4; ++pc) wt[pc] = aw0[pc] * im + aw1[pc] * em;
        const float* cjp = coord + (size_t)(b * 256 + j) * 12;
        const float4 cj0 = *reinterpret_cast<const float4*>(cjp);
        const float4 cj1 = *reinterpret_cast<const float4*>(cjp + 4);
        const float4 cj2 = *reinterpret_cast<const float4*>(cjp + 8);
        float cjv[12] = {cj0.x, cj0.y, cj0.z, cj0.w, cj1.x, cj1.y, cj1.z, cj1.w,
                         cj2.x, cj2.y, cj2.z, cj2.w};
        float accC[12];
        #pragma unroll
        for (int q2 = 0; q2 < 12; ++q2) accC[q2] = (cil[q2] - cjv[q2]) * wt[q2 / 3];
        float dacc = im + em;
        #pragma unroll
        for (int s = 1; s < 16; s <<= 1) {
            #pragma unroll
            for (int q2 = 0; q2 < 12; ++q2) accC[q2] += __shfl_xor(accC[q2], s, 64);
            dacc += __shfl_xor(dacc, s, 64);
        }
        if (l == 0) {
            #pragma unroll
            for (int q2 = 0; q2 < 12; ++q2) redC[w][q2] = accC[q2];
            redD[w] = dacc;
        }
    }
    __syncthreads();
    if (t < 13) {
        float s = 0.f;
        if (t < 12) {
            #pragma unroll
            for (int ww = 0; ww < 8; ++ww) s += redC[ww][t];
        } else {
            #pragma unroll
            for (int ww = 0; ww < 8; ++ww) s += redD[ww];
        }
        aggC[(size_t)blk * 16 + t] = s;
    }
}

// ---------------- node update + LayerNorm + coord finalize + agg sum + eA/eB ----------------
__global__ __launch_bounds__(128) void k_node(
    const float* __restrict__ h, const float* __restrict__ coord,
    const float* __restrict__ aggP, const float* __restrict__ aggC,
    const float* __restrict__ rel0, const float* __restrict__ rel1,
    const float* __restrict__ nw1, const float* __restrict__ nb1,
    const float* __restrict__ nw2, const float* __restrict__ nb2,
    const float* __restrict__ lnw, const float* __restrict__ lnb,
    const float* __restrict__ edge_w1, const float* __restrict__ edge_b1,
    float* __restrict__ h_out, float* __restrict__ coord_out,
    float* __restrict__ eA, float* __restrict__ eB)
{
    const int r = blockIdx.x, t = threadIdx.x;
    __shared__ float hl[128], aIl[128], aEl[128], a0l[128], a1l[128], hidl[128], hnl[128];
    if (t < 12) {
        const float s = aggC[(size_t)(2 * r) * 16 + t] + aggC[(size_t)(2 * r + 1) * 16 + t];
        const float d = aggC[(size_t)(2 * r) * 16 + 12] + aggC[(size_t)(2 * r + 1) * 16 + 12] + 2.56e-4f;
        coord_out[r * 12 + t] = coord[r * 12 + t] + s / d;
    }
    hl[t]  = h[r * 128 + t];
    {
        float sI = 0.f, sE = 0.f;
        #pragma unroll
        for (int p = 0; p < 8; ++p) {
            const size_t base = ((size_t)(8 * r) + p) * 256;
            sI += aggP[base + t];
            sE += aggP[base + 128 + t];
        }
        aIl[t] = sI; aEl[t] = sE;
    }
    __syncthreads();
    float a0 = 0.f, a1 = 0.f;
    #pragma unroll 8
    for (int k = 0; k < 128; ++k) { a0 += aIl[k] * rel0[k * 128 + t]; a1 += aEl[k] * rel1[k * 128 + t]; }
    a0l[t] = a0; a1l[t] = a1;
    __syncthreads();
    float pre = nb1[t];
    #pragma unroll 8
    for (int k = 0; k < 128; ++k) pre += hl[k]  * nw1[k * 128 + t];
    #pragma unroll 8
    for (int k = 0; k < 128; ++k) pre += a0l[k] * nw1[(128 + k) * 128 + t];
    #pragma unroll 8
    for (int k = 0; k < 128; ++k) pre += a1l[k] * nw1[(256 + k) * 128 + t];
    hidl[t] = silu(pre);
    __syncthreads();
    float upd = nb2[t];
    #pragma unroll 8
    for (int k = 0; k < 128; ++k) upd += hidl[k] * nw2[k * 128 + t];
    const float x = hl[t] + upd;
    float s = x, s2 = x * x;
    #pragma unroll
    for (int d = 1; d < 64; d <<= 1) { s += __shfl_xor(s, d, 64); s2 += __shfl_xor(s2, d, 64); }
    __shared__ float rs[2], rs2[2];
    const int wv = t >> 6;
    if ((t & 63) == 0) { rs[wv] = s; rs2[wv] = s2; }
    __syncthreads();
    const float S = rs[0] + rs[1], S2 = rs2[0] + rs2[1];
    const float mu = S * (1.f / 128.f);
    const float var = S2 * (1.f / 128.f) - mu * mu;
    const float hn = (x - mu) * rsqrtf(var + 1e-5f) * lnw[t] + lnb[t];
    h_out[r * 128 + t] = hn;
    hnl[t] = hn;
    __syncthreads();
    // fused pre_msg (edge path): eA = h_new@W1[0:128]+b1, eB = h_new@W1[128:256]
    float accA = edge_b1[t], accB = 0.f;
    #pragma unroll 8
    for (int k = 0; k < 128; ++k) {
        accA += hnl[k] * edge_w1[k * 128 + t];
        accB += hnl[k] * edge_w1[(128 + k) * 128 + t];
    }
    eA[r * 128 + t] = accA;
    eB[r * 128 + t] = accB;
}

// ---------------- edge update via MFMA (jh-split) ----------------
__global__ __launch_bounds__(512) void k_edge_mfma(
    const float* __restrict__ z,
    const float* __restrict__ eA, const float* __restrict__ eB,
    const unsigned short* __restrict__ wE1A,
    const unsigned short* __restrict__ wEW2A,
    const float* __restrict__ eb2,
    float* __restrict__ z_out)
{
    const int blk = blockIdx.x;
    const int bi  = blk >> 1;
    const int jh  = blk & 1;
    const int b   = bi >> 8;
    const int t   = threadIdx.x;
    const int w   = t >> 6, l = t & 63, g = l >> 4, l15 = l & 15;

    __shared__ __align__(16) unsigned short hidm[128 * 136];  // rows reused fp32 for z_new
    __shared__ float eAl[128];
    __shared__ float eb2l[64];

    if (t < 128)      eAl[t] = eA[bi * 128 + t];
    else if (t < 192) eb2l[t - 128] = eb2[t - 128];
    __syncthreads();

    const int j   = jh * 128 + w * 16 + l15;
    const int row = w * 16 + l15;
    const size_t rb = (size_t)row * 136;

    // GEMM1 (K=64), rf-halves to keep peak VGPR low
    #pragma unroll 1
    for (int rfh = 0; rfh < 2; ++rfh) {
        asm volatile("" ::: "memory");
        f32x4 a1[4];
        #pragma unroll
        for (int rf2 = 0; rf2 < 4; ++rf2) a1[rf2] = (f32x4){0.f, 0.f, 0.f, 0.f};
        #pragma unroll
        for (int kk = 0; kk < 2; ++kk) {
            const bf16x8 bf = cvt8(z + (size_t)(bi * 256 + j) * 64 + kk * 32 + g * 8);
            #pragma unroll
            for (int rf2 = 0; rf2 < 4; ++rf2)
                a1[rf2] = __builtin_amdgcn_mfma_f32_16x16x32_bf16(
                    *reinterpret_cast<const bf16x8*>(wE1A + ((kk * 8 + rfh * 4 + rf2) * 64 + l) * 8), bf, a1[rf2], 0, 0, 0);
        }
        const float* eBrow = eB + (size_t)(b * 256 + j) * 128;
        #pragma unroll
        for (int rf2 = 0; rf2 < 4; ++rf2) {
            const int cb = (rfh * 4 + rf2) * 16 + g * 4;
            const float4 e4 = *reinterpret_cast<const float4*>(eBrow + cb);
            union { __bf16 b4[4]; unsigned long long u; } pk;
            pk.b4[0] = (__bf16)silu(a1[rf2][0] + eAl[cb + 0] + e4.x);
            pk.b4[1] = (__bf16)silu(a1[rf2][1] + eAl[cb + 1] + e4.y);
            pk.b4[2] = (__bf16)silu(a1[rf2][2] + eAl[cb + 2] + e4.z);
            pk.b4[3] = (__bf16)silu(a1[rf2][3] + eAl[cb + 3] + e4.w);
            *reinterpret_cast<unsigned long long*>(hidm + rb + cb) = pk.u;
        }
    }
    __builtin_amdgcn_wave_barrier();

    // GEMM2: K=128, 64 output rows (p)
    f32x4 a2[4];
    #pragma unroll
    for (int rf = 0; rf < 4; ++rf) a2[rf] = (f32x4){0.f, 0.f, 0.f, 0.f};
    #pragma unroll
    for (int kk2 = 0; kk2 < 4; ++kk2) {
        const bf16x8 bf2 = *reinterpret_cast<const bf16x8*>(hidm + rb + kk2 * 32 + g * 8);
        #pragma unroll
        for (int rf = 0; rf < 4; ++rf)
            a2[rf] = __builtin_amdgcn_mfma_f32_16x16x32_bf16(
                *reinterpret_cast<const bf16x8*>(wEW2A + ((kk2 * 4 + rf) * 64 + l) * 8), bf2, a2[rf], 0, 0, 0);
    }
    __builtin_amdgcn_wave_barrier();

    // z_new row (fp32) overwrites the hidden LDS row
    float* zst = reinterpret_cast<float*>(hidm + rb);
    #pragma unroll
    for (int rf = 0; rf < 4; ++rf) {
        const int p0 = rf * 16 + g * 4;
        float4 v;
        v.x = a2[rf][0] + eb2l[p0 + 0];
        v.y = a2[rf][1] + eb2l[p0 + 1];
        v.z = a2[rf][2] + eb2l[p0 + 2];
        v.w = a2[rf][3] + eb2l[p0 + 3];
        *reinterpret_cast<float4*>(zst + p0) = v;
    }
    __builtin_amdgcn_wave_barrier();

    // coalesced z_out write: wave's 16 rows, 256B contiguous per row
    #pragma unroll
    for (int it = 0; it < 4; ++it) {
        const int chunk = it * 64 + l;
        const int rl = chunk >> 4, oct = chunk & 15;
        const float4 v = *reinterpret_cast<const float4*>(
            reinterpret_cast<const float*>(hidm + (size_t)(w * 16 + rl) * 136) + oct * 4);
        *reinterpret_cast<float4*>(z_out + (size_t)(bi * 256 + jh * 128 + w * 16 + rl) * 64 + oct * 4) = v;
    }
}

extern "C" void kernel_launch(void* const* d_in, const int* in_sizes, int n_in,
                              void* d_out, int out_size, void* d_ws, size_t ws_size,
                              hipStream_t stream)
{
    (void)in_sizes; (void)n_in; (void)out_size; (void)ws_size;
    const float* coord  = (const float*)d_in[2];
    const float* h      = (const float*)d_in[3];
    const float* z      = (const float*)d_in[4];
    const float* intra  = (const float*)d_in[5];
    const float* inter  = (const float*)d_in[6];
    const float* msg_w1 = (const float*)d_in[7];
    const float* msg_b1 = (const float*)d_in[8];
    const float* msg_w2 = (const float*)d_in[9];
    const float* msg_b2 = (const float*)d_in[10];
    const float* rel_w0 = (const float*)d_in[11];
    const float* rel_w1 = (const float*)d_in[12];
    const float* node_w1= (const float*)d_in[13];
    const float* node_b1= (const float*)d_in[14];
    const float* node_w2= (const float*)d_in[15];
    const float* node_b2= (const float*)d_in[16];
    const float* edge_w1= (const float*)d_in[17];
    const float* edge_b1= (const float*)d_in[18];
    const float* edge_w2= (const float*)d_in[19];
    const float* edge_b2= (const float*)d_in[20];
    const float* c0w1   = (const float*)d_in[21];
    const float* c0w2   = (const float*)d_in[23];
    const float* c1w1   = (const float*)d_in[24];
    const float* c1w2   = (const float*)d_in[26];
    const float* lnw    = (const float*)d_in[27];
    const float* lnb    = (const float*)d_in[28];

    float* out       = (float*)d_out;
    float* coord_out = out;                       // [N,L,C,3]   12288
    float* h_out     = out + 12288;               // [N,L,D]     131072
    float* z_out     = out + 12288 + 131072;      // [N,L,L,P]   16777216

    float* ws      = (float*)d_ws;
    float* partial = ws;                          // 16384
    float* rnorm   = ws + 16384;                  // 64
    float* hA      = ws + 16448;                  // 131072
    float* aggP    = hA + 131072;                 // 2097152 (2048 blocks x 4 jg x 256)
    float* aggC    = aggP + 2097152;              // 32768 (2048 blocks x 16)
    float* eA      = aggC + 32768;                // 131072
    float* eB      = eA + 131072;                 // 131072
    unsigned short* wsA    = (unsigned short*)(eB + 131072);  // 32768 us
    unsigned short* wsMsgA = wsA + 32768;                     // 28672 us
    unsigned short* wsW2A  = wsMsgA + 28672;                  // 16384 us
    unsigned short* wsE1A  = wsW2A + 16384;                   //  8192 us
    unsigned short* wsEW2A = wsE1A + 8192;                    //  8192 us
    unsigned short* wsCW2  = wsEW2A + 8192;                   //  4096 us (coord W2 frags)
    unsigned short* h_bf   = wsCW2 + 4096;                    // 131072 us

    k_prep<<<1984, 256, 0, stream>>>(coord, h, msg_w1, msg_b1, msg_w2,
                                     edge_w1, edge_w2, c0w1, c1w1, c0w2, c1w2,
                                     partial, hA, wsA, wsMsgA, wsW2A,
                                     wsE1A, wsEW2A, wsCW2, h_bf);
    k_norm_finish<<<1, 256, 0, stream>>>(partial, rnorm);
    k_msg_mfma<<<2048, 512, 0, stream>>>(coord, z, h_bf, hA,
                                         wsMsgA, wsW2A, wsA, wsCW2,
                                         msg_b2, rnorm, intra, inter, aggP, aggC);
    k_node<<<1024, 128, 0, stream>>>(h, coord, aggP, aggC, rel_w0, rel_w1,
                                     node_w1, node_b1, node_w2, node_b2, lnw, lnb,
                                     edge_w1, edge_b1, h_out, coord_out, eA, eB);
    k_edge_mfma<<<2048, 512, 0, stream>>>(z, eA, eB, wsE1A, wsEW2A, edge_b2, z_out);
}

// Round 20
// 183.815 us; speedup vs baseline: 1.0250x; 1.0250x over previous
//
#include <hip/hip_runtime.h>

// SABlock: EGNN-style block. N=4, L=256, D=128, P=64, C=4.
// R20 = exact revert to R18 best (184.5us): z_bf prep restored (R19 lesson: inline cvt8
// of fp32 z in GEMM1's chain costs more than the 100MB prep conversion saves).
//   k_prep      : norm_partial | pack frags | pre_hA | h,z->bf16
//   k_norm_finish : rnorm[16]
//   k_msg_mfma  : GEMM1 -> silu -> GEMM2 (m LDS-only) -> agg partials -> coord MLPs on MFMA
//   k_node      : node MLP + LayerNorm + coord finalize + agg sum + fused eA/eB
//   k_edge_mfma : jh-split (2048 blocks)

#define DEV static __device__ __forceinline__

// Fast silu: x * rcp(1+exp(-x)); ~1ulp rcp error invisible after bf16 truncation.
DEV float silu(float x) {
    const float e = __expf(-x);
    return x * __builtin_amdgcn_rcpf(1.0f + e);
}

DEV float bf2f(unsigned short u) {
    unsigned int v = ((unsigned int)u) << 16;
    float f;
    __builtin_memcpy(&f, &v, 4);
    return f;
}
DEV unsigned short f2bf(float f) {
    unsigned int x;
    __builtin_memcpy(&x, &f, 4);
    x += 0x7fffu + ((x >> 16) & 1u);
    return (unsigned short)(x >> 16);
}

struct __align__(8) US4 { unsigned short x, y, z, w; };

typedef __bf16 bf16x8 __attribute__((ext_vector_type(8)));
typedef float  f32x4  __attribute__((ext_vector_type(4)));

DEV bf16x8 cvt8(const float* p) {
    const float4 a = *reinterpret_cast<const float4*>(p);
    const float4 c = *reinterpret_cast<const float4*>(p + 4);
    bf16x8 r;
    r[0] = (__bf16)a.x; r[1] = (__bf16)a.y; r[2] = (__bf16)a.z; r[3] = (__bf16)a.w;
    r[4] = (__bf16)c.x; r[5] = (__bf16)c.y; r[6] = (__bf16)c.z; r[7] = (__bf16)c.w;
    return r;
}

// ---------------- fat prep kernel ----------------
// blk ranges: [0,1024) norm_partial | [1024,1152) pack coord w1 | [1152,1328) pack msg
//             [1328,1392) pack edge | [1392,1904) pre_hA | [1904,1920) pack coord W2
//             [1920,1984) h->bf16 | [1984,10176) z->bf16 (only when use_bf)
__global__ __launch_bounds__(256) void k_prep(
    const float* __restrict__ coord, const float* __restrict__ h,
    const float* __restrict__ z,
    const float* __restrict__ msg_w1, const float* __restrict__ msg_b1,
    const float* __restrict__ msg_w2,
    const float* __restrict__ edge_w1, const float* __restrict__ edge_w2,
    const float* __restrict__ c0w1, const float* __restrict__ c1w1,
    const float* __restrict__ c0w2, const float* __restrict__ c1w2,
    float* __restrict__ partial, float* __restrict__ hA,
    unsigned short* __restrict__ wsA, unsigned short* __restrict__ wsMsgA,
    unsigned short* __restrict__ wsW2A,
    unsigned short* __restrict__ wE1A, unsigned short* __restrict__ wEW2A,
    unsigned short* __restrict__ wsCW2,
    unsigned short* __restrict__ h_bf, unsigned short* __restrict__ z_bf)
{
    const int blk = blockIdx.x;
    const int t = threadIdx.x;
    __shared__ float red[4][16];
    __shared__ float hl2[2][128];

    if (blk < 1024) {
        const int r = blk * 256 + t;
        const int b = r >> 16, rem = r & 0xFFFF, i = rem >> 8, j = rem & 255;
        const float* ci = coord + (b * 256 + i) * 12;
        const float* cj = coord + (b * 256 + j) * 12;
        float cd[4][3];
        #pragma unroll
        for (int c = 0; c < 4; ++c)
            #pragma unroll
            for (int x = 0; x < 3; ++x)
                cd[c][x] = ci[c * 3 + x] - cj[c * 3 + x];
        float sq[16];
        #pragma unroll
        for (int m = 0; m < 4; ++m)
            #pragma unroll
            for (int p = 0; p < 4; ++p) {
                float v = cd[m][0] * cd[p][0] + cd[m][1] * cd[p][1] + cd[m][2] * cd[p][2];
                sq[m * 4 + p] = v * v;
            }
        #pragma unroll
        for (int s = 1; s < 64; s <<= 1)
            #pragma unroll
            for (int qq = 0; qq < 16; ++qq)
                sq[qq] += __shfl_xor(sq[qq], s, 64);
        const int wave = t >> 6, lane = t & 63;
        if (lane == 0)
            #pragma unroll
            for (int qq = 0; qq < 16; ++qq) red[wave][qq] = sq[qq];
        __syncthreads();
        if (t < 16)
            partial[blk * 16 + t] = red[0][t] + red[1][t] + red[2][t] + red[3][t];
    } else if (blk < 1152) {
        const int o = (blk - 1024) * 256 + t;         // < 32768
        const int p  = o >> 14;
        const int r  = o & 16383;
        const int jj = r & 7, l = (r >> 3) & 63, rf = (r >> 9) & 7, kk = r >> 12;
        const int k = kk * 32 + ((l >> 4) << 3) + jj;
        const int c = (rf << 4) + (l & 15);
        const float* W = p ? c1w1 : c0w1;
        wsA[o] = f2bf(W[k * 128 + c]);
    } else if (blk < 1328) {
        const int o = (blk - 1152) * 256 + t;         // < 45056
        if (o < 16384) {
            const int jj = o & 7, l = (o >> 3) & 63, rf = (o >> 9) & 7, kk = o >> 12;
            const int k = kk * 32 + ((l >> 4) << 3) + jj;
            const int c = (rf << 4) + (l & 15);
            wsMsgA[o] = f2bf(msg_w1[(128 + k) * 128 + c]);
        } else if (o < 20480) {
            const int o2 = o - 16384;
            const int jj = o2 & 7, l = (o2 >> 3) & 63, rf = (o2 >> 9) & 7;
            const int k = ((l >> 4) << 3) + jj;
            const int c = (rf << 4) + (l & 15);
            wsMsgA[o] = (k < 16) ? f2bf(msg_w1[(256 + k) * 128 + c]) : (unsigned short)0;
        } else if (o < 28672) {
            const int o3 = o - 20480;
            const int jj = o3 & 7, l = (o3 >> 3) & 63, rf = (o3 >> 9) & 7, kk = o3 >> 12;
            const int k = kk * 32 + ((l >> 4) << 3) + jj;
            const int c = (rf << 4) + (l & 15);
            wsMsgA[o] = f2bf(msg_w1[(272 + k) * 128 + c]);
        } else {
            const int o2 = o - 28672;                 // < 16384
            const int jj = o2 & 7, l = (o2 >> 3) & 63, rf = (o2 >> 9) & 7, kk2 = o2 >> 12;
            const int c  = kk2 * 32 + ((l >> 4) << 3) + jj;
            const int c2 = (rf << 4) + (l & 15);
            wsW2A[o2] = f2bf(msg_w2[c * 128 + c2]);
        }
    } else if (blk < 1392) {
        const int o = (blk - 1328) * 256 + t;         // < 16384
        if (o < 8192) {
            const int jj = o & 7, l = (o >> 3) & 63, rf = (o >> 9) & 7, kk = o >> 12;
            const int k = kk * 32 + ((l >> 4) << 3) + jj;
            const int c = (rf << 4) + (l & 15);
            wE1A[o] = f2bf(edge_w1[(256 + k) * 128 + c]);
        } else {
            const int o2 = o - 8192;
            const int jj = o2 & 7, l = (o2 >> 3) & 63, rf = (o2 >> 9) & 3, kk2 = o2 >> 11;
            const int k = kk2 * 32 + ((l >> 4) << 3) + jj;
            const int p = (rf << 4) + (l & 15);
            wEW2A[o2] = f2bf(edge_w2[k * 64 + p]);
        }
    } else if (blk < 1904) {
        const int rr = (blk - 1392) * 2 + (t >> 7);
        const int c = t & 127;
        hl2[t >> 7][c] = h[rr * 128 + c];
        __syncthreads();
        float acc = msg_b1[c];
        #pragma unroll 8
        for (int k = 0; k < 128; ++k) acc += hl2[t >> 7][k] * msg_w1[k * 128 + c];
        hA[rr * 128 + c] = acc;
    } else if (blk < 1920) {
        // coord W2 as zero-padded 16x128 A-frags: A[pr][k] = W2[k][pr] for pr<4 else 0
        const int o = (blk - 1904) * 256 + t;         // < 4096
        const int p = o >> 11;
        const int r = o & 2047;
        const int jj = r & 7, l = (r >> 3) & 63, kk = (r >> 9) & 3;
        const int k = kk * 32 + ((l >> 4) << 3) + jj;
        const int pr = l & 15;
        const float* W2 = p ? c1w2 : c0w2;
        wsCW2[o] = (pr < 4) ? f2bf(W2[k * 4 + pr]) : (unsigned short)0;
    } else if (blk < 1984) {
        const int i0 = (blk - 1920) * 2048 + t * 8;   // < 131072
        const bf16x8 v = cvt8(h + i0);
        *reinterpret_cast<bf16x8*>(h_bf + i0) = v;
    } else {
        const size_t i0 = (size_t)(blk - 1984) * 2048 + t * 8;  // < 16777216
        const bf16x8 v = cvt8(z + i0);
        *reinterpret_cast<bf16x8*>(z_bf + i0) = v;
    }
}

__global__ __launch_bounds__(256) void k_norm_finish(const float* __restrict__ partial,
                                                     float* __restrict__ rnorm)
{
    const int t = threadIdx.x;
    const int cc = t & 15, g = t >> 4;
    float s = 0.f;
    for (int k = 0; k < 64; ++k) s += partial[(g * 64 + k) * 16 + cc];
    __shared__ float red[16][17];
    red[g][cc] = s;
    __syncthreads();
    if (t < 16) {
        float tot = 0.f;
        #pragma unroll
        for (int gg = 0; gg < 16; ++gg) tot += red[gg][t];
        rnorm[t] = 1.0f / fmaxf(sqrtf(tot), 1e-12f);
    }
}

// ---------------- message MLP + coord MLPs + aggregates, all fused ----------------
template<int ZBF>
__global__ __launch_bounds__(512) void k_msg_mfma(
    const float* __restrict__ coord, const float* __restrict__ h,
    const float* __restrict__ z,
    const unsigned short* __restrict__ h_bf, const unsigned short* __restrict__ z_bf,
    const float* __restrict__ hA,
    const unsigned short* __restrict__ wsMsgA,
    const unsigned short* __restrict__ wsW2A,
    const unsigned short* __restrict__ wsA,
    const unsigned short* __restrict__ wsCW2,
    const float* __restrict__ msg_b2, const float* __restrict__ rnorm,
    const float* __restrict__ intra, const float* __restrict__ inter,
    float* __restrict__ aggP, float* __restrict__ aggC)
{
    const int blk  = blockIdx.x;
    const int bi   = blk >> 1;
    const int jh   = blk & 1;            // which 128-row half of the (b,i) tile
    const int b    = bi >> 8;
    const int t    = threadIdx.x;
    const int w    = t >> 6, l = t & 63, g = l >> 4, l15 = l & 15;

    __shared__ __align__(16) unsigned short A1[20480];        // 40960 B: GEMM1 frags -> W2 frags -> coord frags
    __shared__ __align__(16) unsigned short hidm[128 * 136];  // 34816 B
    __shared__ float hAl[128], b2l[128];
    __shared__ float iml[128], eml[128];                      // this block's mask rows
    __shared__ float cil[12];
    __shared__ float rnl[16];
    __shared__ float redC[8][12];
    __shared__ float redD[8];

    {
        const float4* src = reinterpret_cast<const float4*>(wsMsgA);
        float4* dst = reinterpret_cast<float4*>(A1);
        #pragma unroll
        for (int it = 0; it < 5; ++it) dst[it * 512 + t] = src[it * 512 + t];  // 40 KB
    }
    if (t < 12) cil[t] = coord[bi * 12 + t];
    if (t < 16) rnl[t] = rnorm[t];
    if (t < 128)      hAl[t] = hA[bi * 128 + t];
    else if (t < 256) b2l[t - 128] = msg_b2[t - 128];
    else if (t < 384) iml[t - 256] = intra[(size_t)bi * 256 + jh * 128 + (t - 256)];
    else              eml[t - 384] = inter[(size_t)bi * 256 + jh * 128 + (t - 384)];
    __syncthreads();

    const int j   = jh * 128 + w * 16 + l15;   // j in [0,256)
    const int row = w * 16 + l15;
    const size_t rb = (size_t)row * 136;

    // rad B-frag inline (K=32 slot: k = g*8+e, real for k<16, zero-padded above)
    bf16x8 radB;
    {
        const float* cjp = coord + (size_t)(b * 256 + j) * 12;   // 48B rows, 16B-aligned
        const float4 cj0 = *reinterpret_cast<const float4*>(cjp);
        const float4 cj1 = *reinterpret_cast<const float4*>(cjp + 4);
        const float4 cj2 = *reinterpret_cast<const float4*>(cjp + 8);
        float cd[12];
        cd[0] = cil[0] - cj0.x; cd[1]  = cil[1]  - cj0.y; cd[2]  = cil[2]  - cj0.z;
        cd[3] = cil[3] - cj0.w; cd[4]  = cil[4]  - cj1.x; cd[5]  = cil[5]  - cj1.y;
        cd[6] = cil[6] - cj1.z; cd[7]  = cil[7]  - cj1.w; cd[8]  = cil[8]  - cj2.x;
        cd[9] = cil[9] - cj2.y; cd[10] = cil[10] - cj2.z; cd[11] = cil[11] - cj2.w;
        #pragma unroll
        for (int e = 0; e < 8; ++e) {
            const int k = g * 8 + e;
            float v = 0.f;
            if (k < 16) {
                const int mm = k >> 2, pp = k & 3;
                v = (cd[mm*3+0]*cd[pp*3+0] + cd[mm*3+1]*cd[pp*3+1] + cd[mm*3+2]*cd[pp*3+2]) * rnl[k];
            }
            radB[e] = (__bf16)v;
        }
    }

    // GEMM1: K=224, rf-halves (a1[4]); hj+rad frags from A1 LDS, z frags from global/L2
    #pragma unroll 1
    for (int rfh = 0; rfh < 2; ++rfh) {
        asm volatile("" ::: "memory");
        f32x4 a1[4];
        #pragma unroll
        for (int rf2 = 0; rf2 < 4; ++rf2) a1[rf2] = (f32x4){0.f, 0.f, 0.f, 0.f};

        #pragma unroll
        for (int kk = 0; kk < 4; ++kk) {
            bf16x8 bf;
            if constexpr (ZBF) bf = *reinterpret_cast<const bf16x8*>(h_bf + (size_t)(b * 256 + j) * 128 + kk * 32 + g * 8);
            else               bf = cvt8(h + (size_t)(b * 256 + j) * 128 + kk * 32 + g * 8);
            #pragma unroll
            for (int rf2 = 0; rf2 < 4; ++rf2)
                a1[rf2] = __builtin_amdgcn_mfma_f32_16x16x32_bf16(
                    *reinterpret_cast<const bf16x8*>(A1 + ((kk * 8 + rfh * 4 + rf2) * 64 + l) * 8), bf, a1[rf2], 0, 0, 0);
        }
        #pragma unroll
        for (int kk = 0; kk < 2; ++kk) {
            bf16x8 bf;
            if constexpr (ZBF) bf = *reinterpret_cast<const bf16x8*>(z_bf + (size_t)(bi * 256 + j) * 64 + kk * 32 + g * 8);
            else               bf = cvt8(z + (size_t)(bi * 256 + j) * 64 + kk * 32 + g * 8);
            #pragma unroll
            for (int rf2 = 0; rf2 < 4; ++rf2)
                a1[rf2] = __builtin_amdgcn_mfma_f32_16x16x32_bf16(
                    *reinterpret_cast<const bf16x8*>(wsMsgA + 20480 + ((kk * 8 + rfh * 4 + rf2) * 64 + l) * 8), bf, a1[rf2], 0, 0, 0);
        }
        #pragma unroll
        for (int rf2 = 0; rf2 < 4; ++rf2)
            a1[rf2] = __builtin_amdgcn_mfma_f32_16x16x32_bf16(
                *reinterpret_cast<const bf16x8*>(A1 + 16384 + ((rfh * 4 + rf2) * 64 + l) * 8), radB, a1[rf2], 0, 0, 0);

        // hidden = silu(acc + hA[c]) -> bf16 into this lane's hidm row (this half's columns)
        #pragma unroll
        for (int rf2 = 0; rf2 < 4; ++rf2) {
            const int cb = (rfh * 4 + rf2) * 16 + g * 4;
            union { __bf16 b4[4]; unsigned long long u; } pk;
            #pragma unroll
            for (int r = 0; r < 4; ++r) pk.b4[r] = (__bf16)silu(a1[rf2][r] + hAl[cb + r]);
            *reinterpret_cast<unsigned long long*>(hidm + rb + cb) = pk.u;
        }
    }

    // ---- stage GEMM2 W2 A-frags into A1's now-dead LDS ----
    __syncthreads();   // all waves' GEMM1 A1 reads complete
    {
        const float4* src = reinterpret_cast<const float4*>(wsW2A);
        float4* dst = reinterpret_cast<float4*>(A1);
        #pragma unroll
        for (int it = 0; it < 4; ++it) dst[it * 512 + t] = src[it * 512 + t];  // 32 KB
    }
    __syncthreads();

    // GEMM2: m^T = W2^T x hidden^T (W2 A-frags from LDS)
    {
        f32x4 a2[8];
        #pragma unroll
        for (int rf = 0; rf < 8; ++rf) a2[rf] = (f32x4){0.f, 0.f, 0.f, 0.f};
        #pragma unroll
        for (int kk2 = 0; kk2 < 4; ++kk2) {
            const bf16x8 bf2 = *reinterpret_cast<const bf16x8*>(hidm + rb + kk2 * 32 + g * 8);
            #pragma unroll
            for (int rf = 0; rf < 8; ++rf)
                a2[rf] = __builtin_amdgcn_mfma_f32_16x16x32_bf16(
                    *reinterpret_cast<const bf16x8*>(A1 + ((kk2 * 8 + rf) * 64 + l) * 8), bf2, a2[rf], 0, 0, 0);
        }
        __builtin_amdgcn_wave_barrier();

        // epilogue: +b2, pack m (bf16) over the hidm row. m stays in LDS only.
        #pragma unroll
        for (int rf = 0; rf < 8; ++rf) {
            const int cb = rf * 16 + g * 4;
            union { __bf16 b4[4]; unsigned long long u; } pk;
            #pragma unroll
            for (int r = 0; r < 4; ++r) pk.b4[r] = (__bf16)(a2[rf][r] + b2l[cb + r]);
            *reinterpret_cast<unsigned long long*>(hidm + rb + cb) = pk.u;
        }
    }

    __syncthreads();   // all hidm rows (m) visible; all A1 GEMM2 reads complete

    // ---- fused masked-aggregate partials: masks from LDS ----
    {
        const int c  = t & 127;
        const int jg = t >> 7;          // 0..3, rows jg*32 .. jg*32+31
        float aIp = 0.f, aEp = 0.f;
        #pragma unroll 8
        for (int r2 = 0; r2 < 32; ++r2) {
            const int row2 = jg * 32 + r2;
            const float mv = bf2f(hidm[(size_t)row2 * 136 + c]);
            aIp += mv * iml[row2];
            aEp += mv * eml[row2];
        }
        aggP[((size_t)blk * 4 + jg) * 256 + c]       = aIp;
        aggP[((size_t)blk * 4 + jg) * 256 + 128 + c] = aEp;
    }

    // ---- fused coord MLPs, fully on MFMA ----
    __syncthreads();   // agg done in all waves; A1 free for re-staging
    {
        const float4* src = reinterpret_cast<const float4*>(wsA);          // p0 w1 frags, 32 KB
        float4* dst = reinterpret_cast<float4*>(A1);
        #pragma unroll
        for (int it = 0; it < 4; ++it) dst[it * 512 + t] = src[it * 512 + t];
        const float4* srcW = reinterpret_cast<const float4*>(wsCW2);       // both W2 frag sets, 8 KB
        reinterpret_cast<float4*>(A1 + 16384)[t] = srcW[t];
    }
    __syncthreads();

    // m B-frags, read once, reused for both p (hidm rows are wave-local)
    bf16x8 bfm[4];
    #pragma unroll
    for (int kk2 = 0; kk2 < 4; ++kk2)
        bfm[kk2] = *reinterpret_cast<const bf16x8*>(hidm + rb + kk2 * 32 + g * 8);

    f32x4 aw0, aw1;
    {
        // p=0 GEMM1
        f32x4 ac[8];
        #pragma unroll
        for (int rf = 0; rf < 8; ++rf) ac[rf] = (f32x4){0.f, 0.f, 0.f, 0.f};
        #pragma unroll
        for (int kk2 = 0; kk2 < 4; ++kk2)
            #pragma unroll
            for (int rf = 0; rf < 8; ++rf)
                ac[rf] = __builtin_amdgcn_mfma_f32_16x16x32_bf16(
                    *reinterpret_cast<const bf16x8*>(A1 + ((kk2 * 8 + rf) * 64 + l) * 8), bfm[kk2], ac[rf], 0, 0, 0);
        #pragma unroll
        for (int rf = 0; rf < 8; ++rf) {
            const int cb = rf * 16 + g * 4;
            union { __bf16 b4[4]; unsigned long long u; } pk;
            #pragma unroll
            for (int r = 0; r < 4; ++r) pk.b4[r] = (__bf16)silu(ac[rf][r]);
            *reinterpret_cast<unsigned long long*>(hidm + rb + cb) = pk.u;
        }
        __builtin_amdgcn_wave_barrier();
        aw0 = (f32x4){0.f, 0.f, 0.f, 0.f};
        #pragma unroll
        for (int kk2 = 0; kk2 < 4; ++kk2) {
            const bf16x8 bh = *reinterpret_cast<const bf16x8*>(hidm + rb + kk2 * 32 + g * 8);
            aw0 = __builtin_amdgcn_mfma_f32_16x16x32_bf16(
                *reinterpret_cast<const bf16x8*>(A1 + 16384 + ((kk2 * 64) + l) * 8), bh, aw0, 0, 0, 0);
        }
    }
    __syncthreads();   // all A1 p0 reads done
    {
        const float4* src = reinterpret_cast<const float4*>(wsA + 16384);  // p1 w1 frags
        float4* dst = reinterpret_cast<float4*>(A1);
        #pragma unroll
        for (int it = 0; it < 4; ++it) dst[it * 512 + t] = src[it * 512 + t];
    }
    __syncthreads();
    {
        // p=1 GEMM1 (bfm still live)
        f32x4 ac[8];
        #pragma unroll
        for (int rf = 0; rf < 8; ++rf) ac[rf] = (f32x4){0.f, 0.f, 0.f, 0.f};
        #pragma unroll
        for (int kk2 = 0; kk2 < 4; ++kk2)
            #pragma unroll
            for (int rf = 0; rf < 8; ++rf)
                ac[rf] = __builtin_amdgcn_mfma_f32_16x16x32_bf16(
                    *reinterpret_cast<const bf16x8*>(A1 + ((kk2 * 8 + rf) * 64 + l) * 8), bfm[kk2], ac[rf], 0, 0, 0);
        #pragma unroll
        for (int rf = 0; rf < 8; ++rf) {
            const int cb = rf * 16 + g * 4;
            union { __bf16 b4[4]; unsigned long long u; } pk;
            #pragma unroll
            for (int r = 0; r < 4; ++r) pk.b4[r] = (__bf16)silu(ac[rf][r]);
            *reinterpret_cast<unsigned long long*>(hidm + rb + cb) = pk.u;
        }
        __builtin_amdgcn_wave_barrier();
        aw1 = (f32x4){0.f, 0.f, 0.f, 0.f};
        #pragma unroll
        for (int kk2 = 0; kk2 < 4; ++kk2) {
            const bf16x8 bh = *reinterpret_cast<const bf16x8*>(hidm + rb + kk2 * 32 + g * 8);
            aw1 = __builtin_amdgcn_mfma_f32_16x16x32_bf16(
                *reinterpret_cast<const bf16x8*>(A1 + 16384 + 2048 + ((kk2 * 64) + l) * 8), bh, aw1, 0, 0, 0);
        }
    }

    // epilogue: g==0 lanes hold wt rows 0..3 (channels) for col l15 = their j
    if (g == 0) {
        const float im = iml[row];
        const float em = eml[row];
        float wt[4];
        #pragma unroll
        for (int pc = 0; pc < 4; ++pc) wt[pc] = aw0[pc] * im + aw1[pc] * em;
        const float* cjp = coord + (size_t)(b * 256 + j) * 12;
        const float4 cj0 = *reinterpret_cast<const float4*>(cjp);
        const float4 cj1 = *reinterpret_cast<const float4*>(cjp + 4);
        const float4 cj2 = *reinterpret_cast<const float4*>(cjp + 8);
        float cjv[12] = {cj0.x, cj0.y, cj0.z, cj0.w, cj1.x, cj1.y, cj1.z, cj1.w,
                         cj2.x, cj2.y, cj2.z, cj2.w};
        float accC[12];
        #pragma unroll
        for (int q2 = 0; q2 < 12; ++q2) accC[q2] = (cil[q2] - cjv[q2]) * wt[q2 / 3];
        float dacc = im + em;
        #pragma unroll
        for (int s = 1; s < 16; s <<= 1) {
            #pragma unroll
            for (int q2 = 0; q2 < 12; ++q2) accC[q2] += __shfl_xor(accC[q2], s, 64);
            dacc += __shfl_xor(dacc, s, 64);
        }
        if (l == 0) {
            #pragma unroll
            for (int q2 = 0; q2 < 12; ++q2) redC[w][q2] = accC[q2];
            redD[w] = dacc;
        }
    }
    __syncthreads();
    if (t < 13) {
        float s = 0.f;
        if (t < 12) {
            #pragma unroll
            for (int ww = 0; ww < 8; ++ww) s += redC[ww][t];
        } else {
            #pragma unroll
            for (int ww = 0; ww < 8; ++ww) s += redD[ww];
        }
        aggC[(size_t)blk * 16 + t] = s;
    }
}

// ---------------- node update + LayerNorm + coord finalize + agg sum + eA/eB ----------------
__global__ __launch_bounds__(128) void k_node(
    const float* __restrict__ h, const float* __restrict__ coord,
    const float* __restrict__ aggP, const float* __restrict__ aggC,
    const float* __restrict__ rel0, const float* __restrict__ rel1,
    const float* __restrict__ nw1, const float* __restrict__ nb1,
    const float* __restrict__ nw2, const float* __restrict__ nb2,
    const float* __restrict__ lnw, const float* __restrict__ lnb,
    const float* __restrict__ edge_w1, const float* __restrict__ edge_b1,
    float* __restrict__ h_out, float* __restrict__ coord_out,
    float* __restrict__ eA, float* __restrict__ eB)
{
    const int r = blockIdx.x, t = threadIdx.x;
    __shared__ float hl[128], aIl[128], aEl[128], a0l[128], a1l[128], hidl[128], hnl[128];
    if (t < 12) {
        const float s = aggC[(size_t)(2 * r) * 16 + t] + aggC[(size_t)(2 * r + 1) * 16 + t];
        const float d = aggC[(size_t)(2 * r) * 16 + 12] + aggC[(size_t)(2 * r + 1) * 16 + 12] + 2.56e-4f;
        coord_out[r * 12 + t] = coord[r * 12 + t] + s / d;
    }
    hl[t]  = h[r * 128 + t];
    {
        float sI = 0.f, sE = 0.f;
        #pragma unroll
        for (int p = 0; p < 8; ++p) {
            const size_t base = ((size_t)(8 * r) + p) * 256;
            sI += aggP[base + t];
            sE += aggP[base + 128 + t];
        }
        aIl[t] = sI; aEl[t] = sE;
    }
    __syncthreads();
    float a0 = 0.f, a1 = 0.f;
    #pragma unroll 8
    for (int k = 0; k < 128; ++k) { a0 += aIl[k] * rel0[k * 128 + t]; a1 += aEl[k] * rel1[k * 128 + t]; }
    a0l[t] = a0; a1l[t] = a1;
    __syncthreads();
    float pre = nb1[t];
    #pragma unroll 8
    for (int k = 0; k < 128; ++k) pre += hl[k]  * nw1[k * 128 + t];
    #pragma unroll 8
    for (int k = 0; k < 128; ++k) pre += a0l[k] * nw1[(128 + k) * 128 + t];
    #pragma unroll 8
    for (int k = 0; k < 128; ++k) pre += a1l[k] * nw1[(256 + k) * 128 + t];
    hidl[t] = silu(pre);
    __syncthreads();
    float upd = nb2[t];
    #pragma unroll 8
    for (int k = 0; k < 128; ++k) upd += hidl[k] * nw2[k * 128 + t];
    const float x = hl[t] + upd;
    float s = x, s2 = x * x;
    #pragma unroll
    for (int d = 1; d < 64; d <<= 1) { s += __shfl_xor(s, d, 64); s2 += __shfl_xor(s2, d, 64); }
    __shared__ float rs[2], rs2[2];
    const int wv = t >> 6;
    if ((t & 63) == 0) { rs[wv] = s; rs2[wv] = s2; }
    __syncthreads();
    const float S = rs[0] + rs[1], S2 = rs2[0] + rs2[1];
    const float mu = S * (1.f / 128.f);
    const float var = S2 * (1.f / 128.f) - mu * mu;
    const float hn = (x - mu) * rsqrtf(var + 1e-5f) * lnw[t] + lnb[t];
    h_out[r * 128 + t] = hn;
    hnl[t] = hn;
    __syncthreads();
    // fused pre_msg (edge path): eA = h_new@W1[0:128]+b1, eB = h_new@W1[128:256]
    float accA = edge_b1[t], accB = 0.f;
    #pragma unroll 8
    for (int k = 0; k < 128; ++k) {
        accA += hnl[k] * edge_w1[k * 128 + t];
        accB += hnl[k] * edge_w1[(128 + k) * 128 + t];
    }
    eA[r * 128 + t] = accA;
    eB[r * 128 + t] = accB;
}

// ---------------- edge update via MFMA (jh-split) ----------------
template<int ZBF>
__global__ __launch_bounds__(512) void k_edge_mfma(
    const float* __restrict__ z, const unsigned short* __restrict__ z_bf,
    const float* __restrict__ eA, const float* __restrict__ eB,
    const unsigned short* __restrict__ wE1A,
    const unsigned short* __restrict__ wEW2A,
    const float* __restrict__ eb2,
    float* __restrict__ z_out)
{
    const int blk = blockIdx.x;
    const int bi  = blk >> 1;
    const int jh  = blk & 1;
    const int b   = bi >> 8;
    const int t   = threadIdx.x;
    const int w   = t >> 6, l = t & 63, g = l >> 4, l15 = l & 15;

    __shared__ __align__(16) unsigned short hidm[128 * 136];  // rows reused fp32 for z_new
    __shared__ float eAl[128];
    __shared__ float eb2l[64];

    if (t < 128)      eAl[t] = eA[bi * 128 + t];
    else if (t < 192) eb2l[t - 128] = eb2[t - 128];
    __syncthreads();

    const int j   = jh * 128 + w * 16 + l15;
    const int row = w * 16 + l15;
    const size_t rb = (size_t)row * 136;

    // GEMM1 (K=64), rf-halves to keep peak VGPR low
    #pragma unroll 1
    for (int rfh = 0; rfh < 2; ++rfh) {
        asm volatile("" ::: "memory");
        f32x4 a1[4];
        #pragma unroll
        for (int rf2 = 0; rf2 < 4; ++rf2) a1[rf2] = (f32x4){0.f, 0.f, 0.f, 0.f};
        #pragma unroll
        for (int kk = 0; kk < 2; ++kk) {
            bf16x8 bf;
            if constexpr (ZBF) bf = *reinterpret_cast<const bf16x8*>(z_bf + (size_t)(bi * 256 + j) * 64 + kk * 32 + g * 8);
            else               bf = cvt8(z + (size_t)(bi * 256 + j) * 64 + kk * 32 + g * 8);
            #pragma unroll
            for (int rf2 = 0; rf2 < 4; ++rf2)
                a1[rf2] = __builtin_amdgcn_mfma_f32_16x16x32_bf16(
                    *reinterpret_cast<const bf16x8*>(wE1A + ((kk * 8 + rfh * 4 + rf2) * 64 + l) * 8), bf, a1[rf2], 0, 0, 0);
        }
        const float* eBrow = eB + (size_t)(b * 256 + j) * 128;
        #pragma unroll
        for (int rf2 = 0; rf2 < 4; ++rf2) {
            const int cb = (rfh * 4 + rf2) * 16 + g * 4;
            const float4 e4 = *reinterpret_cast<const float4*>(eBrow + cb);
            union { __bf16 b4[4]; unsigned long long u; } pk;
            pk.b4[0] = (__bf16)silu(a1[rf2][0] + eAl[cb + 0] + e4.x);
            pk.b4[1] = (__bf16)silu(a1[rf2][1] + eAl[cb + 1] + e4.y);
            pk.b4[2] = (__bf16)silu(a1[rf2][2] + eAl[cb + 2] + e4.z);
            pk.b4[3] = (__bf16)silu(a1[rf2][3] + eAl[cb + 3] + e4.w);
            *reinterpret_cast<unsigned long long*>(hidm + rb + cb) = pk.u;
        }
    }
    __builtin_amdgcn_wave_barrier();

    // GEMM2: K=128, 64 output rows (p)
    f32x4 a2[4];
    #pragma unroll
    for (int rf = 0; rf < 4; ++rf) a2[rf] = (f32x4){0.f, 0.f, 0.f, 0.f};
    #pragma unroll
    for (int kk2 = 0; kk2 < 4; ++kk2) {
        const bf16x8 bf2 = *reinterpret_cast<const bf16x8*>(hidm + rb + kk2 * 32 + g * 8);
        #pragma unroll
        for (int rf = 0; rf < 4; ++rf)
            a2[rf] = __builtin_amdgcn_mfma_f32_16x16x32_bf16(
                *reinterpret_cast<const bf16x8*>(wEW2A + ((kk2 * 4 + rf) * 64 + l) * 8), bf2, a2[rf], 0, 0, 0);
    }
    __builtin_amdgcn_wave_barrier();

    // z_new row (fp32) overwrites the hidden LDS row
    float* zst = reinterpret_cast<float*>(hidm + rb);
    #pragma unroll
    for (int rf = 0; rf < 4; ++rf) {
        const int p0 = rf * 16 + g * 4;
        float4 v;
        v.x = a2[rf][0] + eb2l[p0 + 0];
        v.y = a2[rf][1] + eb2l[p0 + 1];
        v.z = a2[rf][2] + eb2l[p0 + 2];
        v.w = a2[rf][3] + eb2l[p0 + 3];
        *reinterpret_cast<float4*>(zst + p0) = v;
    }
    __builtin_amdgcn_wave_barrier();

    // coalesced z_out write: wave's 16 rows, 256B contiguous per row
    #pragma unroll
    for (int it = 0; it < 4; ++it) {
        const int chunk = it * 64 + l;
        const int rl = chunk >> 4, oct = chunk & 15;
        const float4 v = *reinterpret_cast<const float4*>(
            reinterpret_cast<const float*>(hidm + (size_t)(w * 16 + rl) * 136) + oct * 4);
        *reinterpret_cast<float4*>(z_out + (size_t)(bi * 256 + jh * 128 + w * 16 + rl) * 64 + oct * 4) = v;
    }
}

extern "C" void kernel_launch(void* const* d_in, const int* in_sizes, int n_in,
                              void* d_out, int out_size, void* d_ws, size_t ws_size,
                              hipStream_t stream)
{
    (void)in_sizes; (void)n_in; (void)out_size;
    const float* coord  = (const float*)d_in[2];
    const float* h      = (const float*)d_in[3];
    const float* z      = (const float*)d_in[4];
    const float* intra  = (const float*)d_in[5];
    const float* inter  = (const float*)d_in[6];
    const float* msg_w1 = (const float*)d_in[7];
    const float* msg_b1 = (const float*)d_in[8];
    const float* msg_w2 = (const float*)d_in[9];
    const float* msg_b2 = (const float*)d_in[10];
    const float* rel_w0 = (const float*)d_in[11];
    const float* rel_w1 = (const float*)d_in[12];
    const float* node_w1= (const float*)d_in[13];
    const float* node_b1= (const float*)d_in[14];
    const float* node_w2= (const float*)d_in[15];
    const float* node_b2= (const float*)d_in[16];
    const float* edge_w1= (const float*)d_in[17];
    const float* edge_b1= (const float*)d_in[18];
    const float* edge_w2= (const float*)d_in[19];
    const float* edge_b2= (const float*)d_in[20];
    const float* c0w1   = (const float*)d_in[21];
    const float* c0w2   = (const float*)d_in[23];
    const float* c1w1   = (const float*)d_in[24];
    const float* c1w2   = (const float*)d_in[26];
    const float* lnw    = (const float*)d_in[27];
    const float* lnb    = (const float*)d_in[28];

    float* out       = (float*)d_out;
    float* coord_out = out;                       // [N,L,C,3]   12288
    float* h_out     = out + 12288;               // [N,L,D]     131072
    float* z_out     = out + 12288 + 131072;      // [N,L,L,P]   16777216

    float* ws      = (float*)d_ws;
    float* partial = ws;                          // 16384
    float* rnorm   = ws + 16384;                  // 64
    float* hA      = ws + 16448;                  // 131072
    float* aggP    = hA + 131072;                 // 2097152 (2048 blocks x 4 jg x 256)
    float* aggC    = aggP + 2097152;              // 32768 (2048 blocks x 16)
    float* eA      = aggC + 32768;                // 131072
    float* eB      = eA + 131072;                 // 131072
    unsigned short* wsA    = (unsigned short*)(eB + 131072);  // 32768 us
    unsigned short* wsMsgA = wsA + 32768;                     // 28672 us
    unsigned short* wsW2A  = wsMsgA + 28672;                  // 16384 us
    unsigned short* wsE1A  = wsW2A + 16384;                   //  8192 us
    unsigned short* wsEW2A = wsE1A + 8192;                    //  8192 us
    unsigned short* wsCW2  = wsEW2A + 8192;                   //  4096 us (coord W2 frags)
    unsigned short* h_bf   = wsCW2 + 4096;                    // 131072 us
    unsigned short* z_bf   = h_bf + 131072;                   // 16777216 us (33.5 MB)
    const size_t ws_need = (size_t)((char*)(z_bf + 16777216) - (char*)d_ws);
    const int use_bf = (ws_size >= ws_need) ? 1 : 0;

    const int prep_grid = use_bf ? 10176 : 1920;
    k_prep<<<prep_grid, 256, 0, stream>>>(coord, h, z, msg_w1, msg_b1, msg_w2,
                                          edge_w1, edge_w2, c0w1, c1w1, c0w2, c1w2,
                                          partial, hA, wsA, wsMsgA, wsW2A,
                                          wsE1A, wsEW2A, wsCW2, h_bf, z_bf);
    k_norm_finish<<<1, 256, 0, stream>>>(partial, rnorm);
    if (use_bf) {
        k_msg_mfma<1><<<2048, 512, 0, stream>>>(coord, h, z, h_bf, z_bf, hA,
                                                wsMsgA, wsW2A, wsA, wsCW2,
                                                msg_b2, rnorm, intra, inter, aggP, aggC);
    } else {
        k_msg_mfma<0><<<2048, 512, 0, stream>>>(coord, h, z, h_bf, z_bf, hA,
                                                wsMsgA, wsW2A, wsA, wsCW2,
                                                msg_b2, rnorm, intra, inter, aggP, aggC);
    }
    k_node<<<1024, 128, 0, stream>>>(h, coord, aggP, aggC, rel_w0, rel_w1,
                                     node_w1, node_b1, node_w2, node_b2, lnw, lnb,
                                     edge_w1, edge_b1, h_out, coord_out, eA, eB);
    if (use_bf) {
        k_edge_mfma<1><<<2048, 512, 0, stream>>>(z, z_bf, eA, eB, wsE1A, wsEW2A, edge_b2, z_out);
    } else {
        k_edge_mfma<0><<<2048, 512, 0, stream>>>(z, z_bf, eA, eB, wsE1A, wsEW2A, edge_b2, z_out);
    }
}